// Round 3
// baseline (584.452 us; speedup 1.0000x reference)
//
#include <hip/hip_runtime.h>
#include <hip/hip_bf16.h>

#define IN_DIM 512
#define HEADS 8
#define HID 8
#define OUT_DIM 7
#define NEG_SLOPE 0.2f

// ---------------- GEMM1: h1 = x @ W1  (+ fused asrc1/adst1) ----------------
#define G1_ROWS 16
__global__ __launch_bounds__(256) void gemm1_kernel(
    const float* __restrict__ x, const float* __restrict__ W1,
    const float* __restrict__ as1, const float* __restrict__ ad1,
    float* __restrict__ h1, float* __restrict__ asrc1, float* __restrict__ adst1,
    int n)
{
    __shared__ float Ws[128][64];       // 32 KB k-tile of W1
    __shared__ float Xs[G1_ROWS][128];  // 8 KB x tile
    int t = threadIdx.x;
    int col = t & 63;          // output column (= h*8+c)
    int rs  = t >> 6;          // row slot 0..3
    int r0  = blockIdx.x * G1_ROWS;
    float acc[4] = {0.f, 0.f, 0.f, 0.f};

    for (int k0 = 0; k0 < IN_DIM; k0 += 128) {
        __syncthreads();
        // stage W1[k0..k0+127][0..63] : 2048 float4
        const float4* w4 = (const float4*)(W1 + k0 * 64);
        float4* ws4 = (float4*)(&Ws[0][0]);
        #pragma unroll
        for (int j = 0; j < 8; ++j) ws4[t + j * 256] = w4[t + j * 256];
        // stage x tile: 16 rows x 128 cols = 512 float4
        #pragma unroll
        for (int j = 0; j < 2; ++j) {
            int idx = t + j * 256;          // 0..511
            int row = idx >> 5, kq = idx & 31;
            int gr = r0 + row;
            float4 v = make_float4(0.f, 0.f, 0.f, 0.f);
            if (gr < n) v = ((const float4*)(x + (size_t)gr * IN_DIM + k0))[kq];
            ((float4*)(&Xs[row][0]))[kq] = v;
        }
        __syncthreads();
        #pragma unroll
        for (int kk = 0; kk < 128; ++kk) {
            float wv = Ws[kk][col];
            acc[0] = fmaf(Xs[rs][kk], wv, acc[0]);
            acc[1] = fmaf(Xs[rs + 4][kk], wv, acc[1]);
            acc[2] = fmaf(Xs[rs + 8][kk], wv, acc[2]);
            acc[3] = fmaf(Xs[rs + 12][kk], wv, acc[3]);
        }
    }
    // epilogue: store h1 (NO bias here — reference adds b only after aggregation),
    // and reduce asrc/adst over c within each head's 8 consecutive lanes.
    int h = col >> 3, c = col & 7;
    float asv = as1[col];   // att_src1[h][c]
    float adv = ad1[col];
    #pragma unroll
    for (int j = 0; j < 4; ++j) {
        int gr = r0 + rs + j * 4;
        if (gr < n) {
            float v = acc[j];
            h1[(size_t)gr * 64 + col] = v;
            float pa = v * asv, pd = v * adv;
            #pragma unroll
            for (int d = 1; d < 8; d <<= 1) {
                pa += __shfl_xor(pa, d);
                pd += __shfl_xor(pd, d);
            }
            if (c == 0) { asrc1[gr * 8 + h] = pa; adst1[gr * 8 + h] = pd; }
        }
    }
}

// ---------------- CSR build ----------------
__global__ void hist_kernel(const int* __restrict__ dst, int* __restrict__ counts, int E)
{
    int i = blockIdx.x * blockDim.x + threadIdx.x;
    int stride = gridDim.x * blockDim.x;
    for (; i < E; i += stride) atomicAdd(&counts[dst[i]], 1);
}

__global__ __launch_bounds__(1024) void scan_kernel(
    const int* __restrict__ counts, int* __restrict__ offsets,
    int* __restrict__ cursor, int n)
{
    __shared__ int wsums[16];
    __shared__ int carry_s;
    int t = threadIdx.x, lane = t & 63, wid = t >> 6;
    if (t == 0) carry_s = 0;
    __syncthreads();
    for (int base = 0; base < n; base += 4096) {
        int i0 = base + t * 4;
        int v0 = 0, v1 = 0, v2 = 0, v3 = 0;
        if (i0 + 3 < n) {
            int4 v = *(const int4*)(counts + i0);
            v0 = v.x; v1 = v.y; v2 = v.z; v3 = v.w;
        } else {
            if (i0 + 0 < n) v0 = counts[i0 + 0];
            if (i0 + 1 < n) v1 = counts[i0 + 1];
            if (i0 + 2 < n) v2 = counts[i0 + 2];
            if (i0 + 3 < n) v3 = counts[i0 + 3];
        }
        int tsum = v0 + v1 + v2 + v3;
        int inc = tsum;
        #pragma unroll
        for (int d = 1; d < 64; d <<= 1) {
            int u = __shfl_up(inc, d);
            if (lane >= d) inc += u;
        }
        if (lane == 63) wsums[wid] = inc;
        __syncthreads();
        if (t == 0) {
            int run = carry_s;
            #pragma unroll
            for (int w = 0; w < 16; ++w) { int tmp = wsums[w]; wsums[w] = run; run += tmp; }
            carry_s = run;
        }
        __syncthreads();
        int excl = inc - tsum + wsums[wid];
        int o0 = excl, o1 = o0 + v0, o2 = o1 + v1, o3 = o2 + v2;
        if (i0 + 3 < n) {
            *(int4*)(offsets + i0) = make_int4(o0, o1, o2, o3);
            *(int4*)(cursor + i0)  = make_int4(o0, o1, o2, o3);
        } else {
            if (i0 + 0 < n) { offsets[i0 + 0] = o0; cursor[i0 + 0] = o0; }
            if (i0 + 1 < n) { offsets[i0 + 1] = o1; cursor[i0 + 1] = o1; }
            if (i0 + 2 < n) { offsets[i0 + 2] = o2; cursor[i0 + 2] = o2; }
            if (i0 + 3 < n) { offsets[i0 + 3] = o3; cursor[i0 + 3] = o3; }
        }
        __syncthreads();
    }
    if (t == 0) offsets[n] = carry_s;
}

__global__ void scatter_kernel(const int* __restrict__ src, const int* __restrict__ dst,
                               int* __restrict__ cursor, int* __restrict__ csr, int E)
{
    int i = blockIdx.x * blockDim.x + threadIdx.x;
    int stride = gridDim.x * blockDim.x;
    for (; i < E; i += stride) {
        int pos = atomicAdd(&cursor[dst[i]], 1);
        csr[pos] = src[i];
    }
}

// ---------------- Layer-1 edge kernel (softmax + aggregate + fused GEMM2/att2) ---
__global__ __launch_bounds__(256) void l1_edge_kernel(
    const int* __restrict__ offsets, const int* __restrict__ csr,
    const float* __restrict__ asrc1, const float* __restrict__ adst1,
    const float* __restrict__ h1, const float* __restrict__ b1,
    const float* __restrict__ W2, const float* __restrict__ as2,
    const float* __restrict__ ad2,
    float* __restrict__ h2, float* __restrict__ asrc2, float* __restrict__ adst2,
    int n)
{
    __shared__ float w2s[64][9];   // padded stride 9 -> conflict-free per-lane rows
    __shared__ float s_as2[8], s_ad2[8], s_b1[64];
    int t = threadIdx.x;
    if (t < 64) {
        #pragma unroll
        for (int j = 0; j < OUT_DIM; ++j) w2s[t][j] = W2[t * OUT_DIM + j];
        s_b1[t] = b1[t];
        if (t < OUT_DIM) { s_as2[t] = as2[t]; s_ad2[t] = ad2[t]; }
    }
    __syncthreads();

    int lane = t & 63;
    int node = blockIdx.x * 4 + (t >> 6);
    if (node >= n) return;
    int beg = offsets[node], end = offsets[node + 1];

    // ---- Phase A: per-head online max/sum. lane = slot*8 + h ----
    int hA = lane & 7, slot = lane >> 3;
    float advA = adst1[node * 8 + hA];
    float m, s;
    if (slot == 0) {  // self-loop
        float e = asrc1[node * 8 + hA] + advA;
        e = e > 0.f ? e : NEG_SLOPE * e;
        m = e; s = 1.f;
    } else { m = -1e30f; s = 0.f; }
    for (int i = beg + slot; i < end; i += 8) {
        int sn = csr[i];
        float e = asrc1[sn * 8 + hA] + advA;
        e = e > 0.f ? e : NEG_SLOPE * e;
        if (e > m) { s = s * __expf(m - e) + 1.f; m = e; }
        else        s += __expf(e - m);
    }
    #pragma unroll
    for (int d = 8; d < 64; d <<= 1) {   // combine across slots
        float mo = __shfl_xor(m, d), so = __shfl_xor(s, d);
        float mn = fmaxf(m, mo);
        s = s * __expf(m - mn) + so * __expf(mo - mn);
        m = mn;
    }
    // every lane now holds (m,s) for head (lane&7)

    // ---- Phase B: aggregation. lane = h*8 + c  (so h1[src][lane] is coalesced) ----
    int hB = lane >> 3;
    float mB = __shfl(m, hB);
    float sB = __shfl(s, hB);
    float inv = 1.f / fmaxf(sB, 1e-16f);
    float advB = adst1[node * 8 + hB];
    float asB  = asrc1[node * 8 + hB];
    float acc;
    {   // self loop
        float e = asB + advB;
        e = e > 0.f ? e : NEG_SLOPE * e;
        acc = __expf(e - mB) * h1[(size_t)node * 64 + lane];
    }
    for (int i = beg; i < end; ++i) {
        int sn = csr[i];
        float e = asrc1[sn * 8 + hB] + advB;
        e = e > 0.f ? e : NEG_SLOPE * e;
        float p = __expf(e - mB);
        acc = fmaf(p, h1[(size_t)sn * 64 + lane], acc);
    }
    float v = acc * inv + s_b1[lane];
    v = v > 0.f ? v : __expf(v) - 1.f;    // ELU

    // ---- fused GEMM2 (64 -> 7) + att2 ----
    float hj[OUT_DIM];
    #pragma unroll
    for (int j = 0; j < OUT_DIM; ++j) {
        float p = v * w2s[lane][j];
        #pragma unroll
        for (int d = 1; d < 64; d <<= 1) p += __shfl_xor(p, d);
        hj[j] = p;
    }
    float a_s = 0.f, a_d = 0.f;
    #pragma unroll
    for (int j = 0; j < OUT_DIM; ++j) { a_s += hj[j] * s_as2[j]; a_d += hj[j] * s_ad2[j]; }
    if (lane < 8) h2[node * 8 + lane] = (lane < OUT_DIM) ? hj[lane] : 0.f;
    if (lane == 0) { asrc2[node] = a_s; adst2[node] = a_d; }
}

// ---------------- Layer-2 edge kernel -> final logits ----------------
__global__ __launch_bounds__(256) void l2_edge_kernel(
    const int* __restrict__ offsets, const int* __restrict__ csr,
    const float* __restrict__ asrc2, const float* __restrict__ adst2,
    const float* __restrict__ h2, const float* __restrict__ b2,
    float* __restrict__ out, int n)
{
    int t = threadIdx.x, lane = t & 63;
    int node = blockIdx.x * 4 + (t >> 6);
    if (node >= n) return;
    int beg = offsets[node], end = offsets[node + 1];
    float adv = adst2[node];

    // Phase A: scalar online max/sum, 64 edge slots
    float m, s;
    if (lane == 0) {
        float e = asrc2[node] + adv;
        e = e > 0.f ? e : NEG_SLOPE * e;
        m = e; s = 1.f;
    } else { m = -1e30f; s = 0.f; }
    for (int i = beg + lane; i < end; i += 64) {
        int sn = csr[i];
        float e = asrc2[sn] + adv;
        e = e > 0.f ? e : NEG_SLOPE * e;
        if (e > m) { s = s * __expf(m - e) + 1.f; m = e; }
        else        s += __expf(e - m);
    }
    #pragma unroll
    for (int d = 1; d < 64; d <<= 1) {
        float mo = __shfl_xor(m, d), so = __shfl_xor(s, d);
        float mn = fmaxf(m, mo);
        s = s * __expf(m - mn) + so * __expf(mo - mn);
        m = mn;
    }
    float inv = 1.f / fmaxf(s, 1e-16f);

    // Phase B: lane = slot*8 + c ; h2 padded to 8 floats/node
    int c = lane & 7, slot = lane >> 3;
    float acc = 0.f;
    if (slot == 0) {  // self loop
        float e = asrc2[node] + adv;
        e = e > 0.f ? e : NEG_SLOPE * e;
        acc = __expf(e - m) * h2[node * 8 + c];
    }
    for (int i = beg + slot; i < end; i += 8) {
        int sn = csr[i];
        float e = asrc2[sn] + adv;
        e = e > 0.f ? e : NEG_SLOPE * e;
        acc = fmaf(__expf(e - m), h2[sn * 8 + c], acc);
    }
    #pragma unroll
    for (int d = 8; d < 64; d <<= 1) acc += __shfl_xor(acc, d);
    if (lane < OUT_DIM) out[(size_t)node * OUT_DIM + lane] = acc * inv + b2[lane];
}

// ---------------- launch ----------------
static inline size_t rup256(size_t x) { return (x + 255) & ~(size_t)255; }

extern "C" void kernel_launch(void* const* d_in, const int* in_sizes, int n_in,
                              void* d_out, int out_size, void* d_ws, size_t ws_size,
                              hipStream_t stream)
{
    int n = in_sizes[0] / IN_DIM;     // 50000
    int E = in_sizes[1] / 2;          // 1600000

    const float* x   = (const float*)d_in[0];
    const int*   ei  = (const int*)d_in[1];
    const int*   srcv = ei;
    const int*   dstv = ei + E;
    const float* W1  = (const float*)d_in[2];
    const float* as1 = (const float*)d_in[3];
    const float* ad1 = (const float*)d_in[4];
    const float* b1  = (const float*)d_in[5];
    const float* W2  = (const float*)d_in[6];
    const float* as2 = (const float*)d_in[7];
    const float* ad2 = (const float*)d_in[8];
    const float* b2  = (const float*)d_in[9];
    float* out = (float*)d_out;

    char* p = (char*)d_ws;
    auto alloc = [&](size_t bytes) { char* q = p; p += rup256(bytes); return (void*)q; };
    float* h1     = (float*)alloc((size_t)n * 64 * 4);
    float* asrc1  = (float*)alloc((size_t)n * 8 * 4);
    float* adst1  = (float*)alloc((size_t)n * 8 * 4);
    float* h2     = (float*)alloc((size_t)n * 8 * 4);
    float* asrc2  = (float*)alloc((size_t)n * 4);
    float* adst2  = (float*)alloc((size_t)n * 4);
    int*   counts = (int*)alloc((size_t)n * 4);
    int*   offsets= (int*)alloc(((size_t)n + 1) * 4);
    int*   cursor = (int*)alloc((size_t)n * 4);
    int*   csr    = (int*)alloc((size_t)E * 4);

    hipMemsetAsync(counts, 0, (size_t)n * 4, stream);
    hist_kernel<<<2048, 256, 0, stream>>>(dstv, counts, E);
    gemm1_kernel<<<(n + G1_ROWS - 1) / G1_ROWS, 256, 0, stream>>>(
        x, W1, as1, ad1, h1, asrc1, adst1, n);
    scan_kernel<<<1, 1024, 0, stream>>>(counts, offsets, cursor, n);
    scatter_kernel<<<2048, 256, 0, stream>>>(srcv, dstv, cursor, csr, E);
    l1_edge_kernel<<<(n + 3) / 4, 256, 0, stream>>>(
        offsets, csr, asrc1, adst1, h1, b1, W2, as2, ad2, h2, asrc2, adst2, n);
    l2_edge_kernel<<<(n + 3) / 4, 256, 0, stream>>>(
        offsets, csr, asrc2, adst2, h2, b2, out, n);
}

// Round 4
// 490.905 us; speedup vs baseline: 1.1906x; 1.1906x over previous
//
#include <hip/hip_runtime.h>
#include <hip/hip_bf16.h>

#define IN_DIM 512
#define HEADS 8
#define HID 8
#define OUT_DIM 7
#define NEG_SLOPE 0.2f

// ---------------- GEMM1: h1 = x @ W1  (+ fused asrc1/adst1) ----------------
// 64x64 output tile per block, BK=32, 4x4 register tile per thread.
#define BM 64
#define BK 32
__global__ __launch_bounds__(256) void gemm1_kernel(
    const float* __restrict__ x, const float* __restrict__ W1,
    const float* __restrict__ as1, const float* __restrict__ ad1,
    float* __restrict__ h1, float* __restrict__ asrc1, float* __restrict__ adst1,
    int n)
{
    __shared__ float Xt[BK][BM + 4];   // transposed x tile; +4 pad keeps 16B align, spreads banks
    __shared__ float Ws[BK][64];
    int t = threadIdx.x;
    int col4 = (t & 15) * 4;           // 4 consecutive output cols
    int row4 = (t >> 4) * 4;           // 4 consecutive rows
    int r0 = blockIdx.x * BM;
    float acc[4][4] = {{0.f,0.f,0.f,0.f},{0.f,0.f,0.f,0.f},{0.f,0.f,0.f,0.f},{0.f,0.f,0.f,0.f}};

    for (int k0 = 0; k0 < IN_DIM; k0 += BK) {
        __syncthreads();
        // stage W1[k0..k0+31][0..63]: 512 float4, 2 per thread, linear (conflict-free)
        {
            const float4* w4 = (const float4*)(W1 + k0 * 64);
            float4* ws4 = (float4*)(&Ws[0][0]);
            ws4[t] = w4[t];
            ws4[t + 256] = w4[t + 256];
        }
        // stage x transposed: idx -> row = idx>>3 (64 rows), kq = idx&7 (8 float4 = 32 k)
        #pragma unroll
        for (int j = 0; j < 2; ++j) {
            int idx = t + j * 256;
            int row = idx >> 3, kq = idx & 7;
            int gr = r0 + row;
            float4 v = make_float4(0.f, 0.f, 0.f, 0.f);
            if (gr < n) v = *(const float4*)(x + (size_t)gr * IN_DIM + k0 + kq * 4);
            Xt[kq * 4 + 0][row] = v.x;
            Xt[kq * 4 + 1][row] = v.y;
            Xt[kq * 4 + 2][row] = v.z;
            Xt[kq * 4 + 3][row] = v.w;
        }
        __syncthreads();
        #pragma unroll
        for (int kk = 0; kk < BK; ++kk) {
            float4 xv = *(const float4*)(&Xt[kk][row4]);   // quarter-wave broadcast
            float4 wv = *(const float4*)(&Ws[kk][col4]);   // 2-way (free)
            acc[0][0] = fmaf(xv.x, wv.x, acc[0][0]);
            acc[0][1] = fmaf(xv.x, wv.y, acc[0][1]);
            acc[0][2] = fmaf(xv.x, wv.z, acc[0][2]);
            acc[0][3] = fmaf(xv.x, wv.w, acc[0][3]);
            acc[1][0] = fmaf(xv.y, wv.x, acc[1][0]);
            acc[1][1] = fmaf(xv.y, wv.y, acc[1][1]);
            acc[1][2] = fmaf(xv.y, wv.z, acc[1][2]);
            acc[1][3] = fmaf(xv.y, wv.w, acc[1][3]);
            acc[2][0] = fmaf(xv.z, wv.x, acc[2][0]);
            acc[2][1] = fmaf(xv.z, wv.y, acc[2][1]);
            acc[2][2] = fmaf(xv.z, wv.z, acc[2][2]);
            acc[2][3] = fmaf(xv.z, wv.w, acc[2][3]);
            acc[3][0] = fmaf(xv.w, wv.x, acc[3][0]);
            acc[3][1] = fmaf(xv.w, wv.y, acc[3][1]);
            acc[3][2] = fmaf(xv.w, wv.z, acc[3][2]);
            acc[3][3] = fmaf(xv.w, wv.w, acc[3][3]);
        }
    }
    // epilogue: store h1 rows (float4), fused att reductions.
    // cols col4..col4+3 lie in head (col4>>3); thread pairs (l&15)=2m,2m+1 cover head m.
    int head = col4 >> 3;
    float4 asv = *(const float4*)(as1 + col4);
    float4 adv = *(const float4*)(ad1 + col4);
    #pragma unroll
    for (int r = 0; r < 4; ++r) {
        int gr = r0 + row4 + r;
        if (gr < n) {
            *(float4*)(h1 + (size_t)gr * 64 + col4) =
                make_float4(acc[r][0], acc[r][1], acc[r][2], acc[r][3]);
            float pa = acc[r][0] * asv.x + acc[r][1] * asv.y + acc[r][2] * asv.z + acc[r][3] * asv.w;
            float pd = acc[r][0] * adv.x + acc[r][1] * adv.y + acc[r][2] * adv.z + acc[r][3] * adv.w;
            pa += __shfl_xor(pa, 1);   // combine the two col-quads of this head
            pd += __shfl_xor(pd, 1);
            if ((t & 1) == 0) {
                asrc1[gr * 8 + head] = pa;
                adst1[gr * 8 + head] = pd;
            }
        }
    }
}

// ---------------- CSR build ----------------
__global__ void hist_kernel(const int* __restrict__ dst, int* __restrict__ counts, int E)
{
    int i = blockIdx.x * blockDim.x + threadIdx.x;
    int stride = gridDim.x * blockDim.x;
    for (; i < E; i += stride) atomicAdd(&counts[dst[i]], 1);
}

__global__ __launch_bounds__(1024) void scan_kernel(
    const int* __restrict__ counts, int* __restrict__ offsets,
    int* __restrict__ cursor, int n)
{
    __shared__ int wsums[16];
    __shared__ int carry_s;
    int t = threadIdx.x, lane = t & 63, wid = t >> 6;
    if (t == 0) carry_s = 0;
    __syncthreads();
    for (int base = 0; base < n; base += 4096) {
        int i0 = base + t * 4;
        int v0 = 0, v1 = 0, v2 = 0, v3 = 0;
        if (i0 + 3 < n) {
            int4 v = *(const int4*)(counts + i0);
            v0 = v.x; v1 = v.y; v2 = v.z; v3 = v.w;
        } else {
            if (i0 + 0 < n) v0 = counts[i0 + 0];
            if (i0 + 1 < n) v1 = counts[i0 + 1];
            if (i0 + 2 < n) v2 = counts[i0 + 2];
            if (i0 + 3 < n) v3 = counts[i0 + 3];
        }
        int tsum = v0 + v1 + v2 + v3;
        int inc = tsum;
        #pragma unroll
        for (int d = 1; d < 64; d <<= 1) {
            int u = __shfl_up(inc, d);
            if (lane >= d) inc += u;
        }
        if (lane == 63) wsums[wid] = inc;
        __syncthreads();
        if (t == 0) {
            int run = carry_s;
            #pragma unroll
            for (int w = 0; w < 16; ++w) { int tmp = wsums[w]; wsums[w] = run; run += tmp; }
            carry_s = run;
        }
        __syncthreads();
        int excl = inc - tsum + wsums[wid];
        int o0 = excl, o1 = o0 + v0, o2 = o1 + v1, o3 = o2 + v2;
        if (i0 + 3 < n) {
            *(int4*)(offsets + i0) = make_int4(o0, o1, o2, o3);
            *(int4*)(cursor + i0)  = make_int4(o0, o1, o2, o3);
        } else {
            if (i0 + 0 < n) { offsets[i0 + 0] = o0; cursor[i0 + 0] = o0; }
            if (i0 + 1 < n) { offsets[i0 + 1] = o1; cursor[i0 + 1] = o1; }
            if (i0 + 2 < n) { offsets[i0 + 2] = o2; cursor[i0 + 2] = o2; }
            if (i0 + 3 < n) { offsets[i0 + 3] = o3; cursor[i0 + 3] = o3; }
        }
        __syncthreads();
    }
    if (t == 0) offsets[n] = carry_s;
}

__global__ void scatter_kernel(const int* __restrict__ src, const int* __restrict__ dst,
                               int* __restrict__ cursor, int* __restrict__ csr, int E)
{
    int i = blockIdx.x * blockDim.x + threadIdx.x;
    int stride = gridDim.x * blockDim.x;
    for (; i < E; i += stride) {
        int pos = atomicAdd(&cursor[dst[i]], 1);
        csr[pos] = src[i];
    }
}

// ---------------- Layer-1 edge kernel (softmax + aggregate + fused GEMM2/att2) ---
__global__ __launch_bounds__(256) void l1_edge_kernel(
    const int* __restrict__ offsets, const int* __restrict__ csr,
    const float* __restrict__ asrc1, const float* __restrict__ adst1,
    const float* __restrict__ h1, const float* __restrict__ b1,
    const float* __restrict__ W2, const float* __restrict__ as2,
    const float* __restrict__ ad2,
    float* __restrict__ h2, float* __restrict__ asrc2, float* __restrict__ adst2,
    int n)
{
    __shared__ float w2s[64][9];   // padded stride 9 -> conflict-free per-lane rows
    __shared__ float s_as2[8], s_ad2[8], s_b1[64];
    int t = threadIdx.x;
    if (t < 64) {
        #pragma unroll
        for (int j = 0; j < OUT_DIM; ++j) w2s[t][j] = W2[t * OUT_DIM + j];
        s_b1[t] = b1[t];
        if (t < OUT_DIM) { s_as2[t] = as2[t]; s_ad2[t] = ad2[t]; }
    }
    __syncthreads();

    int lane = t & 63;
    int node = blockIdx.x * 4 + (t >> 6);
    if (node >= n) return;
    int beg = offsets[node], end = offsets[node + 1];

    // ---- Phase A: per-head online max/sum. lane = slot*8 + h ----
    int hA = lane & 7, slot = lane >> 3;
    float advA = adst1[node * 8 + hA];
    float m, s;
    if (slot == 0) {  // self-loop
        float e = asrc1[node * 8 + hA] + advA;
        e = e > 0.f ? e : NEG_SLOPE * e;
        m = e; s = 1.f;
    } else { m = -1e30f; s = 0.f; }
    for (int i = beg + slot; i < end; i += 8) {
        int sn = csr[i];
        float e = asrc1[sn * 8 + hA] + advA;
        e = e > 0.f ? e : NEG_SLOPE * e;
        if (e > m) { s = s * __expf(m - e) + 1.f; m = e; }
        else        s += __expf(e - m);
    }
    #pragma unroll
    for (int d = 8; d < 64; d <<= 1) {   // combine across slots
        float mo = __shfl_xor(m, d), so = __shfl_xor(s, d);
        float mn = fmaxf(m, mo);
        s = s * __expf(m - mn) + so * __expf(mo - mn);
        m = mn;
    }
    // every lane now holds (m,s) for head (lane&7)

    // ---- Phase B: aggregation. lane = h*8 + c  (so h1[src][lane] is coalesced) ----
    int hB = lane >> 3;
    float mB = __shfl(m, hB);
    float sB = __shfl(s, hB);
    float inv = 1.f / fmaxf(sB, 1e-16f);
    float advB = adst1[node * 8 + hB];
    float asB  = asrc1[node * 8 + hB];
    float acc;
    {   // self loop
        float e = asB + advB;
        e = e > 0.f ? e : NEG_SLOPE * e;
        acc = __expf(e - mB) * h1[(size_t)node * 64 + lane];
    }
    for (int i = beg; i < end; ++i) {
        int sn = csr[i];
        float e = asrc1[sn * 8 + hB] + advB;
        e = e > 0.f ? e : NEG_SLOPE * e;
        float p = __expf(e - mB);
        acc = fmaf(p, h1[(size_t)sn * 64 + lane], acc);
    }
    float v = acc * inv + s_b1[lane];
    v = v > 0.f ? v : __expf(v) - 1.f;    // ELU

    // ---- fused GEMM2 (64 -> 7) + att2 ----
    float hj[OUT_DIM];
    #pragma unroll
    for (int j = 0; j < OUT_DIM; ++j) {
        float p = v * w2s[lane][j];
        #pragma unroll
        for (int d = 1; d < 64; d <<= 1) p += __shfl_xor(p, d);
        hj[j] = p;
    }
    float a_s = 0.f, a_d = 0.f;
    #pragma unroll
    for (int j = 0; j < OUT_DIM; ++j) { a_s += hj[j] * s_as2[j]; a_d += hj[j] * s_ad2[j]; }
    if (lane < 8) h2[node * 8 + lane] = (lane < OUT_DIM) ? hj[lane] : 0.f;
    if (lane == 0) { asrc2[node] = a_s; adst2[node] = a_d; }
}

// ---------------- Layer-2 edge kernel -> final logits ----------------
__global__ __launch_bounds__(256) void l2_edge_kernel(
    const int* __restrict__ offsets, const int* __restrict__ csr,
    const float* __restrict__ asrc2, const float* __restrict__ adst2,
    const float* __restrict__ h2, const float* __restrict__ b2,
    float* __restrict__ out, int n)
{
    int t = threadIdx.x, lane = t & 63;
    int node = blockIdx.x * 4 + (t >> 6);
    if (node >= n) return;
    int beg = offsets[node], end = offsets[node + 1];
    float adv = adst2[node];

    // Phase A: scalar online max/sum, 64 edge slots
    float m, s;
    if (lane == 0) {
        float e = asrc2[node] + adv;
        e = e > 0.f ? e : NEG_SLOPE * e;
        m = e; s = 1.f;
    } else { m = -1e30f; s = 0.f; }
    for (int i = beg + lane; i < end; i += 64) {
        int sn = csr[i];
        float e = asrc2[sn] + adv;
        e = e > 0.f ? e : NEG_SLOPE * e;
        if (e > m) { s = s * __expf(m - e) + 1.f; m = e; }
        else        s += __expf(e - m);
    }
    #pragma unroll
    for (int d = 1; d < 64; d <<= 1) {
        float mo = __shfl_xor(m, d), so = __shfl_xor(s, d);
        float mn = fmaxf(m, mo);
        s = s * __expf(m - mn) + so * __expf(mo - mn);
        m = mn;
    }
    float inv = 1.f / fmaxf(s, 1e-16f);

    // Phase B: lane = slot*8 + c ; h2 padded to 8 floats/node
    int c = lane & 7, slot = lane >> 3;
    float acc = 0.f;
    if (slot == 0) {  // self loop
        float e = asrc2[node] + adv;
        e = e > 0.f ? e : NEG_SLOPE * e;
        acc = __expf(e - m) * h2[node * 8 + c];
    }
    for (int i = beg + slot; i < end; i += 8) {
        int sn = csr[i];
        float e = asrc2[sn] + adv;
        e = e > 0.f ? e : NEG_SLOPE * e;
        acc = fmaf(__expf(e - m), h2[sn * 8 + c], acc);
    }
    #pragma unroll
    for (int d = 8; d < 64; d <<= 1) acc += __shfl_xor(acc, d);
    if (lane < OUT_DIM) out[(size_t)node * OUT_DIM + lane] = acc * inv + b2[lane];
}

// ---------------- launch ----------------
static inline size_t rup256(size_t x) { return (x + 255) & ~(size_t)255; }

extern "C" void kernel_launch(void* const* d_in, const int* in_sizes, int n_in,
                              void* d_out, int out_size, void* d_ws, size_t ws_size,
                              hipStream_t stream)
{
    int n = in_sizes[0] / IN_DIM;     // 50000
    int E = in_sizes[1] / 2;          // 1600000

    const float* x   = (const float*)d_in[0];
    const int*   ei  = (const int*)d_in[1];
    const int*   srcv = ei;
    const int*   dstv = ei + E;
    const float* W1  = (const float*)d_in[2];
    const float* as1 = (const float*)d_in[3];
    const float* ad1 = (const float*)d_in[4];
    const float* b1  = (const float*)d_in[5];
    const float* W2  = (const float*)d_in[6];
    const float* as2 = (const float*)d_in[7];
    const float* ad2 = (const float*)d_in[8];
    const float* b2  = (const float*)d_in[9];
    float* out = (float*)d_out;

    char* p = (char*)d_ws;
    auto alloc = [&](size_t bytes) { char* q = p; p += rup256(bytes); return (void*)q; };
    float* h1     = (float*)alloc((size_t)n * 64 * 4);
    float* asrc1  = (float*)alloc((size_t)n * 8 * 4);
    float* adst1  = (float*)alloc((size_t)n * 8 * 4);
    float* h2     = (float*)alloc((size_t)n * 8 * 4);
    float* asrc2  = (float*)alloc((size_t)n * 4);
    float* adst2  = (float*)alloc((size_t)n * 4);
    int*   counts = (int*)alloc((size_t)n * 4);
    int*   offsets= (int*)alloc(((size_t)n + 1) * 4);
    int*   cursor = (int*)alloc((size_t)n * 4);
    int*   csr    = (int*)alloc((size_t)E * 4);

    hipMemsetAsync(counts, 0, (size_t)n * 4, stream);
    hist_kernel<<<2048, 256, 0, stream>>>(dstv, counts, E);
    gemm1_kernel<<<(n + BM - 1) / BM, 256, 0, stream>>>(
        x, W1, as1, ad1, h1, asrc1, adst1, n);
    scan_kernel<<<1, 1024, 0, stream>>>(counts, offsets, cursor, n);
    scatter_kernel<<<2048, 256, 0, stream>>>(srcv, dstv, cursor, csr, E);
    l1_edge_kernel<<<(n + 3) / 4, 256, 0, stream>>>(
        offsets, csr, asrc1, adst1, h1, b1, W2, as2, ad2, h2, asrc2, adst2, n);
    l2_edge_kernel<<<(n + 3) / 4, 256, 0, stream>>>(
        offsets, csr, asrc2, adst2, h2, b2, out, n);
}

// Round 5
// 383.762 us; speedup vs baseline: 1.5230x; 1.2792x over previous
//
#include <hip/hip_runtime.h>
#include <hip/hip_bf16.h>

#define IN_DIM 512
#define HEADS 8
#define HID 8
#define OUT_DIM 7
#define NEG_SLOPE 0.2f

// ---------------- GEMM1: h1 = x @ W1  (+ fused asrc1/adst1) ----------------
// 64x64 output tile per block, BK=32, 4x4 register tile per thread.
#define BM 64
#define BK 32
__global__ __launch_bounds__(256) void gemm1_kernel(
    const float* __restrict__ x, const float* __restrict__ W1,
    const float* __restrict__ as1, const float* __restrict__ ad1,
    float* __restrict__ h1, float* __restrict__ asrc1, float* __restrict__ adst1,
    int n)
{
    __shared__ float Xt[BK][BM + 4];   // transposed x tile; +4 pad keeps 16B align, spreads banks
    __shared__ float Ws[BK][64];
    int t = threadIdx.x;
    int col4 = (t & 15) * 4;           // 4 consecutive output cols
    int row4 = (t >> 4) * 4;           // 4 consecutive rows
    int r0 = blockIdx.x * BM;
    float acc[4][4] = {{0.f,0.f,0.f,0.f},{0.f,0.f,0.f,0.f},{0.f,0.f,0.f,0.f},{0.f,0.f,0.f,0.f}};

    for (int k0 = 0; k0 < IN_DIM; k0 += BK) {
        __syncthreads();
        // stage W1[k0..k0+31][0..63]: 512 float4, 2 per thread, linear (conflict-free)
        {
            const float4* w4 = (const float4*)(W1 + k0 * 64);
            float4* ws4 = (float4*)(&Ws[0][0]);
            ws4[t] = w4[t];
            ws4[t + 256] = w4[t + 256];
        }
        // stage x transposed: idx -> row = idx>>3 (64 rows), kq = idx&7 (8 float4 = 32 k)
        #pragma unroll
        for (int j = 0; j < 2; ++j) {
            int idx = t + j * 256;
            int row = idx >> 3, kq = idx & 7;
            int gr = r0 + row;
            float4 v = make_float4(0.f, 0.f, 0.f, 0.f);
            if (gr < n) v = *(const float4*)(x + (size_t)gr * IN_DIM + k0 + kq * 4);
            Xt[kq * 4 + 0][row] = v.x;
            Xt[kq * 4 + 1][row] = v.y;
            Xt[kq * 4 + 2][row] = v.z;
            Xt[kq * 4 + 3][row] = v.w;
        }
        __syncthreads();
        #pragma unroll
        for (int kk = 0; kk < BK; ++kk) {
            float4 xv = *(const float4*)(&Xt[kk][row4]);   // quarter-wave broadcast
            float4 wv = *(const float4*)(&Ws[kk][col4]);   // 2-way (free)
            acc[0][0] = fmaf(xv.x, wv.x, acc[0][0]);
            acc[0][1] = fmaf(xv.x, wv.y, acc[0][1]);
            acc[0][2] = fmaf(xv.x, wv.z, acc[0][2]);
            acc[0][3] = fmaf(xv.x, wv.w, acc[0][3]);
            acc[1][0] = fmaf(xv.y, wv.x, acc[1][0]);
            acc[1][1] = fmaf(xv.y, wv.y, acc[1][1]);
            acc[1][2] = fmaf(xv.y, wv.z, acc[1][2]);
            acc[1][3] = fmaf(xv.y, wv.w, acc[1][3]);
            acc[2][0] = fmaf(xv.z, wv.x, acc[2][0]);
            acc[2][1] = fmaf(xv.z, wv.y, acc[2][1]);
            acc[2][2] = fmaf(xv.z, wv.z, acc[2][2]);
            acc[2][3] = fmaf(xv.z, wv.w, acc[2][3]);
            acc[3][0] = fmaf(xv.w, wv.x, acc[3][0]);
            acc[3][1] = fmaf(xv.w, wv.y, acc[3][1]);
            acc[3][2] = fmaf(xv.w, wv.z, acc[3][2]);
            acc[3][3] = fmaf(xv.w, wv.w, acc[3][3]);
        }
    }
    // epilogue: store h1 rows (float4), fused att reductions.
    int head = col4 >> 3;
    float4 asv = *(const float4*)(as1 + col4);
    float4 adv = *(const float4*)(ad1 + col4);
    #pragma unroll
    for (int r = 0; r < 4; ++r) {
        int gr = r0 + row4 + r;
        if (gr < n) {
            *(float4*)(h1 + (size_t)gr * 64 + col4) =
                make_float4(acc[r][0], acc[r][1], acc[r][2], acc[r][3]);
            float pa = acc[r][0] * asv.x + acc[r][1] * asv.y + acc[r][2] * asv.z + acc[r][3] * asv.w;
            float pd = acc[r][0] * adv.x + acc[r][1] * adv.y + acc[r][2] * adv.z + acc[r][3] * adv.w;
            pa += __shfl_xor(pa, 1);   // combine the two col-quads of this head
            pd += __shfl_xor(pd, 1);
            if ((t & 1) == 0) {
                asrc1[gr * 8 + head] = pa;
                adst1[gr * 8 + head] = pd;
            }
        }
    }
}

// ---------------- CSR build ----------------
__global__ void hist_kernel(const int* __restrict__ dst, int* __restrict__ counts, int E)
{
    int i = blockIdx.x * blockDim.x + threadIdx.x;
    int stride = gridDim.x * blockDim.x;
    for (; i < E; i += stride) atomicAdd(&counts[dst[i]], 1);
}

// Region allocator: contiguous (unordered) CSR regions via one atomic per wave.
__global__ __launch_bounds__(256) void alloc_kernel(
    const int* __restrict__ counts, int* __restrict__ offsets,
    int* __restrict__ cursor, int* __restrict__ total, int n)
{
    int i = blockIdx.x * blockDim.x + threadIdx.x;
    int lane = threadIdx.x & 63;
    int c = (i < n) ? counts[i] : 0;
    int inc = c;
    #pragma unroll
    for (int d = 1; d < 64; d <<= 1) {
        int u = __shfl_up(inc, d);
        if (lane >= d) inc += u;
    }
    int wsum = __shfl(inc, 63);
    int base = 0;
    if (lane == 0) base = atomicAdd(total, wsum);
    base = __shfl(base, 0);
    int excl = base + inc - c;
    if (i < n) { offsets[i] = excl; cursor[i] = excl; }
}

__global__ void scatter_kernel(const int* __restrict__ src, const int* __restrict__ dst,
                               int* __restrict__ cursor, int* __restrict__ csr, int E)
{
    int i = blockIdx.x * blockDim.x + threadIdx.x;
    int stride = gridDim.x * blockDim.x;
    for (; i < E; i += stride) {
        int pos = atomicAdd(&cursor[dst[i]], 1);
        csr[pos] = src[i];
    }
}

// ---------------- Layer-1 edge kernel (softmax + aggregate + fused GEMM2/att2) ---
__global__ __launch_bounds__(256) void l1_edge_kernel(
    const int* __restrict__ offsets, const int* __restrict__ counts,
    const int* __restrict__ csr,
    const float* __restrict__ asrc1, const float* __restrict__ adst1,
    const float* __restrict__ h1, const float* __restrict__ b1,
    const float* __restrict__ W2, const float* __restrict__ as2,
    const float* __restrict__ ad2,
    float* __restrict__ h2, float* __restrict__ asrc2, float* __restrict__ adst2,
    int n)
{
    __shared__ float w2s[64][9];   // padded stride 9
    __shared__ float s_as2[8], s_ad2[8], s_b1[64];
    int t = threadIdx.x;
    if (t < 64) {
        #pragma unroll
        for (int j = 0; j < OUT_DIM; ++j) w2s[t][j] = W2[t * OUT_DIM + j];
        s_b1[t] = b1[t];
        if (t < OUT_DIM) { s_as2[t] = as2[t]; s_ad2[t] = ad2[t]; }
    }
    __syncthreads();

    int lane = t & 63;
    int node = blockIdx.x * 4 + (t >> 6);
    if (node >= n) return;
    int beg = offsets[node];
    int end = beg + counts[node];

    // ---- Phase A: per-head online max/sum. lane = slot*8 + h ----
    int hA = lane & 7, slot = lane >> 3;
    float advA = adst1[node * 8 + hA];
    float m, s, eSelf = 0.f;
    if (slot == 0) {  // self-loop
        float e = asrc1[node * 8 + hA] + advA;
        e = e > 0.f ? e : NEG_SLOPE * e;
        eSelf = e; m = e; s = 1.f;
    } else { m = -1e30f; s = 0.f; }
    {
        int i = beg + slot;
        for (; i + 8 < end; i += 16) {   // 2x unroll per slot
            int sa = csr[i], sb = csr[i + 8];
            float ea = asrc1[sa * 8 + hA] + advA;
            float eb = asrc1[sb * 8 + hA] + advA;
            ea = ea > 0.f ? ea : NEG_SLOPE * ea;
            eb = eb > 0.f ? eb : NEG_SLOPE * eb;
            if (ea > m) { s = s * __expf(m - ea) + 1.f; m = ea; } else s += __expf(ea - m);
            if (eb > m) { s = s * __expf(m - eb) + 1.f; m = eb; } else s += __expf(eb - m);
        }
        for (; i < end; i += 8) {
            int sn = csr[i];
            float e = asrc1[sn * 8 + hA] + advA;
            e = e > 0.f ? e : NEG_SLOPE * e;
            if (e > m) { s = s * __expf(m - e) + 1.f; m = e; } else s += __expf(e - m);
        }
    }
    #pragma unroll
    for (int d = 8; d < 64; d <<= 1) {   // combine across slots
        float mo = __shfl_xor(m, d), so = __shfl_xor(s, d);
        float mn = fmaxf(m, mo);
        s = s * __expf(m - mn) + so * __expf(mo - mn);
        m = mn;
    }
    // lane k holds (m,s) for head k&7; lanes 0..7 hold eSelf for heads 0..7

    // ---- Phase B: 2 edges in parallel (half-waves), float2 channels, 4x unroll ----
    int half = lane >> 5;              // 0 or 1
    int l5 = lane & 31;
    int c0 = l5 * 2;                   // this lane's channel pair
    int hB = l5 >> 2;                  // head of channels c0,c0+1
    float mB = __shfl(m, hB);
    float sB = __shfl(s, hB);
    float inv = 1.f / fmaxf(sB, 1e-16f);
    float advB = __shfl(advA, hB);     // adst1[node*8+hB]
    float eSelfB = __shfl(eSelf, hB);

    float2 acc = make_float2(0.f, 0.f);
    if (half == 0) {  // self loop counted once
        float p = __expf(eSelfB - mB);
        float2 hv = *(const float2*)(h1 + (size_t)node * 64 + c0);
        acc.x = p * hv.x; acc.y = p * hv.y;
    }
    {
        int i = beg + half;
        for (; i + 6 < end; i += 8) {   // 4 edges per half per round
            int s0 = csr[i], s1 = csr[i + 2], s2 = csr[i + 4], s3 = csr[i + 6];
            float a0 = asrc1[s0 * 8 + hB], a1 = asrc1[s1 * 8 + hB];
            float a2 = asrc1[s2 * 8 + hB], a3 = asrc1[s3 * 8 + hB];
            float2 g0 = *(const float2*)(h1 + (size_t)s0 * 64 + c0);
            float2 g1 = *(const float2*)(h1 + (size_t)s1 * 64 + c0);
            float2 g2 = *(const float2*)(h1 + (size_t)s2 * 64 + c0);
            float2 g3 = *(const float2*)(h1 + (size_t)s3 * 64 + c0);
            float e0 = a0 + advB; e0 = e0 > 0.f ? e0 : NEG_SLOPE * e0;
            float e1 = a1 + advB; e1 = e1 > 0.f ? e1 : NEG_SLOPE * e1;
            float e2 = a2 + advB; e2 = e2 > 0.f ? e2 : NEG_SLOPE * e2;
            float e3 = a3 + advB; e3 = e3 > 0.f ? e3 : NEG_SLOPE * e3;
            float p0 = __expf(e0 - mB), p1 = __expf(e1 - mB);
            float p2 = __expf(e2 - mB), p3 = __expf(e3 - mB);
            acc.x = fmaf(p0, g0.x, acc.x); acc.y = fmaf(p0, g0.y, acc.y);
            acc.x = fmaf(p1, g1.x, acc.x); acc.y = fmaf(p1, g1.y, acc.y);
            acc.x = fmaf(p2, g2.x, acc.x); acc.y = fmaf(p2, g2.y, acc.y);
            acc.x = fmaf(p3, g3.x, acc.x); acc.y = fmaf(p3, g3.y, acc.y);
        }
        for (; i < end; i += 2) {       // tail, 1 edge per half
            int sn = csr[i];
            float a = asrc1[sn * 8 + hB];
            float2 g = *(const float2*)(h1 + (size_t)sn * 64 + c0);
            float e = a + advB; e = e > 0.f ? e : NEG_SLOPE * e;
            float p = __expf(e - mB);
            acc.x = fmaf(p, g.x, acc.x); acc.y = fmaf(p, g.y, acc.y);
        }
    }
    // combine the two halves (each lane then has totals for channels c0,c0+1)
    acc.x += __shfl_xor(acc.x, 32);
    acc.y += __shfl_xor(acc.y, 32);

    float vx = acc.x * inv + s_b1[c0];
    float vy = acc.y * inv + s_b1[c0 + 1];
    vx = vx > 0.f ? vx : __expf(vx) - 1.f;    // ELU
    vy = vy > 0.f ? vy : __expf(vy) - 1.f;

    // ---- fused GEMM2 (64 -> 7) + att2 (reduce over 32 lanes; halves identical) ----
    float hj[OUT_DIM];
    #pragma unroll
    for (int j = 0; j < OUT_DIM; ++j) {
        float p = vx * w2s[c0][j] + vy * w2s[c0 + 1][j];
        #pragma unroll
        for (int d = 1; d < 32; d <<= 1) p += __shfl_xor(p, d);
        hj[j] = p;
    }
    float a_s = 0.f, a_d = 0.f;
    #pragma unroll
    for (int j = 0; j < OUT_DIM; ++j) { a_s += hj[j] * s_as2[j]; a_d += hj[j] * s_ad2[j]; }
    if (lane < 8) h2[node * 8 + lane] = (lane < OUT_DIM) ? hj[lane] : 0.f;
    if (lane == 0) { asrc2[node] = a_s; adst2[node] = a_d; }
}

// ---------------- Layer-2 edge kernel -> final logits ----------------
__global__ __launch_bounds__(256) void l2_edge_kernel(
    const int* __restrict__ offsets, const int* __restrict__ counts,
    const int* __restrict__ csr,
    const float* __restrict__ asrc2, const float* __restrict__ adst2,
    const float* __restrict__ h2, const float* __restrict__ b2,
    float* __restrict__ out, int n)
{
    int t = threadIdx.x, lane = t & 63;
    int node = blockIdx.x * 4 + (t >> 6);
    if (node >= n) return;
    int beg = offsets[node];
    int end = beg + counts[node];
    float adv = adst2[node];

    // Phase A: scalar online max/sum, 64 edge slots
    float m, s;
    if (lane == 0) {
        float e = asrc2[node] + adv;
        e = e > 0.f ? e : NEG_SLOPE * e;
        m = e; s = 1.f;
    } else { m = -1e30f; s = 0.f; }
    for (int i = beg + lane; i < end; i += 64) {
        int sn = csr[i];
        float e = asrc2[sn] + adv;
        e = e > 0.f ? e : NEG_SLOPE * e;
        if (e > m) { s = s * __expf(m - e) + 1.f; m = e; }
        else        s += __expf(e - m);
    }
    #pragma unroll
    for (int d = 1; d < 64; d <<= 1) {
        float mo = __shfl_xor(m, d), so = __shfl_xor(s, d);
        float mn = fmaxf(m, mo);
        s = s * __expf(m - mn) + so * __expf(mo - mn);
        m = mn;
    }
    float inv = 1.f / fmaxf(s, 1e-16f);

    // Phase B: lane = slot*8 + c ; h2 padded to 8 floats/node
    int c = lane & 7, slot = lane >> 3;
    float acc = 0.f;
    if (slot == 0) {  // self loop
        float e = asrc2[node] + adv;
        e = e > 0.f ? e : NEG_SLOPE * e;
        acc = __expf(e - m) * h2[node * 8 + c];
    }
    for (int i = beg + slot; i < end; i += 8) {
        int sn = csr[i];
        float e = asrc2[sn] + adv;
        e = e > 0.f ? e : NEG_SLOPE * e;
        acc = fmaf(__expf(e - m), h2[sn * 8 + c], acc);
    }
    #pragma unroll
    for (int d = 8; d < 64; d <<= 1) acc += __shfl_xor(acc, d);
    if (lane < OUT_DIM) out[(size_t)node * OUT_DIM + lane] = acc * inv + b2[lane];
}

// ---------------- launch ----------------
static inline size_t rup256(size_t x) { return (x + 255) & ~(size_t)255; }

extern "C" void kernel_launch(void* const* d_in, const int* in_sizes, int n_in,
                              void* d_out, int out_size, void* d_ws, size_t ws_size,
                              hipStream_t stream)
{
    int n = in_sizes[0] / IN_DIM;     // 50000
    int E = in_sizes[1] / 2;          // 1600000

    const float* x   = (const float*)d_in[0];
    const int*   ei  = (const int*)d_in[1];
    const int*   srcv = ei;
    const int*   dstv = ei + E;
    const float* W1  = (const float*)d_in[2];
    const float* as1 = (const float*)d_in[3];
    const float* ad1 = (const float*)d_in[4];
    const float* b1  = (const float*)d_in[5];
    const float* W2  = (const float*)d_in[6];
    const float* as2 = (const float*)d_in[7];
    const float* ad2 = (const float*)d_in[8];
    const float* b2  = (const float*)d_in[9];
    float* out = (float*)d_out;

    char* p = (char*)d_ws;
    auto alloc = [&](size_t bytes) { char* q = p; p += rup256(bytes); return (void*)q; };
    float* h1     = (float*)alloc((size_t)n * 64 * 4);
    float* asrc1  = (float*)alloc((size_t)n * 8 * 4);
    float* adst1  = (float*)alloc((size_t)n * 8 * 4);
    float* h2     = (float*)alloc((size_t)n * 8 * 4);
    float* asrc2  = (float*)alloc((size_t)n * 4);
    float* adst2  = (float*)alloc((size_t)n * 4);
    int*   counts = (int*)alloc((size_t)n * 4);
    int*   offsets= (int*)alloc(((size_t)n + 1) * 4);
    int*   cursor = (int*)alloc((size_t)n * 4);
    int*   csr    = (int*)alloc((size_t)E * 4);
    int*   total  = (int*)alloc(4);

    hipMemsetAsync(counts, 0, (size_t)n * 4, stream);
    hipMemsetAsync(total, 0, 4, stream);
    hist_kernel<<<2048, 256, 0, stream>>>(dstv, counts, E);
    gemm1_kernel<<<(n + BM - 1) / BM, 256, 0, stream>>>(
        x, W1, as1, ad1, h1, asrc1, adst1, n);
    alloc_kernel<<<(n + 255) / 256, 256, 0, stream>>>(counts, offsets, cursor, total, n);
    scatter_kernel<<<2048, 256, 0, stream>>>(srcv, dstv, cursor, csr, E);
    l1_edge_kernel<<<(n + 3) / 4, 256, 0, stream>>>(
        offsets, counts, csr, asrc1, adst1, h1, b1, W2, as2, ad2, h2, asrc2, adst2, n);
    l2_edge_kernel<<<(n + 3) / 4, 256, 0, stream>>>(
        offsets, counts, csr, asrc2, adst2, h2, b2, out, n);
}

// Round 6
// 237.936 us; speedup vs baseline: 2.4563x; 1.6129x over previous
//
#include <hip/hip_runtime.h>
#include <hip/hip_bf16.h>

#define IN_DIM 512
#define HEADS 8
#define HID 8
#define OUT_DIM 7
#define NEG_SLOPE 0.2f

// ---------------- GEMM1: h1 = x @ W1  (+ fused asrc1/adst1) ----------------
#define BM 64
#define BK 32
__global__ __launch_bounds__(256) void gemm1_kernel(
    const float* __restrict__ x, const float* __restrict__ W1,
    const float* __restrict__ as1, const float* __restrict__ ad1,
    float* __restrict__ h1, float* __restrict__ asrc1, float* __restrict__ adst1,
    int n)
{
    __shared__ float Xt[BK][BM + 4];
    __shared__ float Ws[BK][64];
    int t = threadIdx.x;
    int col4 = (t & 15) * 4;
    int row4 = (t >> 4) * 4;
    int r0 = blockIdx.x * BM;
    float acc[4][4] = {{0.f,0.f,0.f,0.f},{0.f,0.f,0.f,0.f},{0.f,0.f,0.f,0.f},{0.f,0.f,0.f,0.f}};

    for (int k0 = 0; k0 < IN_DIM; k0 += BK) {
        __syncthreads();
        {
            const float4* w4 = (const float4*)(W1 + k0 * 64);
            float4* ws4 = (float4*)(&Ws[0][0]);
            ws4[t] = w4[t];
            ws4[t + 256] = w4[t + 256];
        }
        #pragma unroll
        for (int j = 0; j < 2; ++j) {
            int idx = t + j * 256;
            int row = idx >> 3, kq = idx & 7;
            int gr = r0 + row;
            float4 v = make_float4(0.f, 0.f, 0.f, 0.f);
            if (gr < n) v = *(const float4*)(x + (size_t)gr * IN_DIM + k0 + kq * 4);
            Xt[kq * 4 + 0][row] = v.x;
            Xt[kq * 4 + 1][row] = v.y;
            Xt[kq * 4 + 2][row] = v.z;
            Xt[kq * 4 + 3][row] = v.w;
        }
        __syncthreads();
        #pragma unroll
        for (int kk = 0; kk < BK; ++kk) {
            float4 xv = *(const float4*)(&Xt[kk][row4]);
            float4 wv = *(const float4*)(&Ws[kk][col4]);
            acc[0][0] = fmaf(xv.x, wv.x, acc[0][0]);
            acc[0][1] = fmaf(xv.x, wv.y, acc[0][1]);
            acc[0][2] = fmaf(xv.x, wv.z, acc[0][2]);
            acc[0][3] = fmaf(xv.x, wv.w, acc[0][3]);
            acc[1][0] = fmaf(xv.y, wv.x, acc[1][0]);
            acc[1][1] = fmaf(xv.y, wv.y, acc[1][1]);
            acc[1][2] = fmaf(xv.y, wv.z, acc[1][2]);
            acc[1][3] = fmaf(xv.y, wv.w, acc[1][3]);
            acc[2][0] = fmaf(xv.z, wv.x, acc[2][0]);
            acc[2][1] = fmaf(xv.z, wv.y, acc[2][1]);
            acc[2][2] = fmaf(xv.z, wv.z, acc[2][2]);
            acc[2][3] = fmaf(xv.z, wv.w, acc[2][3]);
            acc[3][0] = fmaf(xv.w, wv.x, acc[3][0]);
            acc[3][1] = fmaf(xv.w, wv.y, acc[3][1]);
            acc[3][2] = fmaf(xv.w, wv.z, acc[3][2]);
            acc[3][3] = fmaf(xv.w, wv.w, acc[3][3]);
        }
    }
    int head = col4 >> 3;
    float4 asv = *(const float4*)(as1 + col4);
    float4 adv = *(const float4*)(ad1 + col4);
    #pragma unroll
    for (int r = 0; r < 4; ++r) {
        int gr = r0 + row4 + r;
        if (gr < n) {
            *(float4*)(h1 + (size_t)gr * 64 + col4) =
                make_float4(acc[r][0], acc[r][1], acc[r][2], acc[r][3]);
            float pa = acc[r][0] * asv.x + acc[r][1] * asv.y + acc[r][2] * asv.z + acc[r][3] * asv.w;
            float pd = acc[r][0] * adv.x + acc[r][1] * adv.y + acc[r][2] * adv.z + acc[r][3] * adv.w;
            pa += __shfl_xor(pa, 1);
            pd += __shfl_xor(pd, 1);
            if ((t & 1) == 0) {
                asrc1[gr * 8 + head] = pa;
                adst1[gr * 8 + head] = pd;
            }
        }
    }
}

// ---------------- CSR build: bucketed two-stage (no global per-node atomics) ----
// Buckets of 256 nodes: b = dst >> 8.  nbuck = ceil(n/256) = 196 for n=50000.

// K1: per-block LDS histogram of buckets -> few global atomics.
__global__ __launch_bounds__(256) void bucket_hist_kernel(
    const int* __restrict__ dst, int* __restrict__ bucketCounts, int E, int nbuck)
{
    __shared__ int cnt[256];
    int t = threadIdx.x;
    cnt[t] = 0;
    __syncthreads();
    int i = blockIdx.x * blockDim.x + t;
    int stride = gridDim.x * blockDim.x;
    for (; i < E; i += stride) atomicAdd(&cnt[dst[i] >> 8], 1);
    __syncthreads();
    if (t < nbuck && cnt[t]) atomicAdd(&bucketCounts[t], cnt[t]);
}

// K2: scan bucket counts -> bucketBase[0..nbuck], init bucketCursor.
__global__ __launch_bounds__(256) void bucket_scan_kernel(
    const int* __restrict__ bucketCounts, int* __restrict__ bucketBase,
    int* __restrict__ bucketCursor, int nbuck)
{
    __shared__ int wsum[4];
    int t = threadIdx.x, lane = t & 63, w = t >> 6;
    int c = (t < nbuck) ? bucketCounts[t] : 0;
    int inc = c;
    #pragma unroll
    for (int d = 1; d < 64; d <<= 1) {
        int u = __shfl_up(inc, d);
        if (lane >= d) inc += u;
    }
    if (lane == 63) wsum[w] = inc;
    __syncthreads();
    if (t == 0) { int run = 0; for (int k = 0; k < 4; ++k) { int tmp = wsum[k]; wsum[k] = run; run += tmp; } }
    __syncthreads();
    int excl = inc - c + wsum[w];
    if (t < nbuck) { bucketBase[t] = excl; bucketCursor[t] = excl; }
    if (t == nbuck) bucketBase[t] = excl;   // total = E
}

// K3: coarse scatter into bucket-ordered tmp. One global atomic per (block,bucket).
#define K3_EPT 16
__global__ __launch_bounds__(256) void coarse_scatter_kernel(
    const int* __restrict__ src, const int* __restrict__ dst,
    int* __restrict__ bucketCursor, unsigned int* __restrict__ tmp, int E)
{
    __shared__ int cnt[256];
    __shared__ int gbase[256];
    int t = threadIdx.x;
    cnt[t] = 0;
    __syncthreads();
    int base = blockIdx.x * (256 * K3_EPT);
    unsigned int pk[K3_EPT];
    unsigned int meta[K3_EPT];   // (rank<<8)|bucket ; 0xFFFFFFFF = invalid
    #pragma unroll
    for (int j = 0; j < K3_EPT; ++j) {
        int i = base + t + j * 256;
        if (i < E) {
            int d = dst[i], s = src[i];
            int b = d >> 8;
            pk[j] = ((unsigned)s << 16) | (unsigned)(d & 0xFF);
            int r = atomicAdd(&cnt[b], 1);
            meta[j] = ((unsigned)r << 8) | (unsigned)b;
        } else {
            meta[j] = 0xFFFFFFFFu; pk[j] = 0;
        }
    }
    __syncthreads();
    if (cnt[t] > 0) gbase[t] = atomicAdd(&bucketCursor[t], cnt[t]);
    __syncthreads();
    #pragma unroll
    for (int j = 0; j < K3_EPT; ++j) {
        if (meta[j] != 0xFFFFFFFFu) {
            int b = meta[j] & 0xFF;
            int r = meta[j] >> 8;
            tmp[gbase[b] + r] = pk[j];
        }
    }
}

// K4: one block per bucket. Fine scatter within L2-resident region; also emits
// per-node offsets/counts (replaces hist+alloc kernels).
__global__ __launch_bounds__(256) void fine_scatter_kernel(
    const unsigned int* __restrict__ tmp, const int* __restrict__ bucketBase,
    int* __restrict__ csr, int* __restrict__ offsets, int* __restrict__ counts, int n)
{
    __shared__ int cnt[256];
    __shared__ int cur[256];
    __shared__ int wsum[4];
    int b = blockIdx.x;
    int t = threadIdx.x, lane = t & 63, w = t >> 6;
    int beg = bucketBase[b], end = bucketBase[b + 1];
    cnt[t] = 0;
    __syncthreads();
    // pass a: per-local-node counts
    for (int i = beg + t; i < end; i += 256)
        atomicAdd(&cnt[tmp[i] & 0xFF], 1);
    __syncthreads();
    // pass b: block scan of 256 counts
    int c = cnt[t];
    int inc = c;
    #pragma unroll
    for (int d = 1; d < 64; d <<= 1) {
        int u = __shfl_up(inc, d);
        if (lane >= d) inc += u;
    }
    if (lane == 63) wsum[w] = inc;
    __syncthreads();
    if (t == 0) { int run = 0; for (int k = 0; k < 4; ++k) { int tt = wsum[k]; wsum[k] = run; run += tt; } }
    __syncthreads();
    int excl = inc - c + wsum[w];
    int node = b * 256 + t;
    if (node < n) { offsets[node] = beg + excl; counts[node] = c; }
    cur[t] = excl;
    __syncthreads();
    // pass c: place (re-read tmp, L2-hot)
    for (int i = beg + t; i < end; i += 256) {
        unsigned int p = tmp[i];
        int r = atomicAdd(&cur[p & 0xFF], 1);
        csr[beg + r] = (int)(p >> 16);
    }
}

// ---------------- Layer-1 edge kernel (softmax + aggregate + fused GEMM2/att2) ---
__global__ __launch_bounds__(256) void l1_edge_kernel(
    const int* __restrict__ offsets, const int* __restrict__ counts,
    const int* __restrict__ csr,
    const float* __restrict__ asrc1, const float* __restrict__ adst1,
    const float* __restrict__ h1, const float* __restrict__ b1,
    const float* __restrict__ W2, const float* __restrict__ as2,
    const float* __restrict__ ad2,
    float* __restrict__ h2, float* __restrict__ asrc2, float* __restrict__ adst2,
    int n)
{
    __shared__ float w2s[64][9];
    __shared__ float s_as2[8], s_ad2[8], s_b1[64];
    int t = threadIdx.x;
    if (t < 64) {
        #pragma unroll
        for (int j = 0; j < OUT_DIM; ++j) w2s[t][j] = W2[t * OUT_DIM + j];
        s_b1[t] = b1[t];
        if (t < OUT_DIM) { s_as2[t] = as2[t]; s_ad2[t] = ad2[t]; }
    }
    __syncthreads();

    int lane = t & 63;
    int node = blockIdx.x * 4 + (t >> 6);
    if (node >= n) return;
    int beg = offsets[node];
    int end = beg + counts[node];

    // ---- Phase A: per-head online max/sum. lane = slot*8 + h ----
    int hA = lane & 7, slot = lane >> 3;
    float advA = adst1[node * 8 + hA];
    float m, s, eSelf = 0.f;
    if (slot == 0) {
        float e = asrc1[node * 8 + hA] + advA;
        e = e > 0.f ? e : NEG_SLOPE * e;
        eSelf = e; m = e; s = 1.f;
    } else { m = -1e30f; s = 0.f; }
    {
        int i = beg + slot;
        for (; i + 8 < end; i += 16) {
            int sa = csr[i], sb = csr[i + 8];
            float ea = asrc1[sa * 8 + hA] + advA;
            float eb = asrc1[sb * 8 + hA] + advA;
            ea = ea > 0.f ? ea : NEG_SLOPE * ea;
            eb = eb > 0.f ? eb : NEG_SLOPE * eb;
            if (ea > m) { s = s * __expf(m - ea) + 1.f; m = ea; } else s += __expf(ea - m);
            if (eb > m) { s = s * __expf(m - eb) + 1.f; m = eb; } else s += __expf(eb - m);
        }
        for (; i < end; i += 8) {
            int sn = csr[i];
            float e = asrc1[sn * 8 + hA] + advA;
            e = e > 0.f ? e : NEG_SLOPE * e;
            if (e > m) { s = s * __expf(m - e) + 1.f; m = e; } else s += __expf(e - m);
        }
    }
    #pragma unroll
    for (int d = 8; d < 64; d <<= 1) {
        float mo = __shfl_xor(m, d), so = __shfl_xor(s, d);
        float mn = fmaxf(m, mo);
        s = s * __expf(m - mn) + so * __expf(mo - mn);
        m = mn;
    }

    // ---- Phase B: 2 edges in parallel (half-waves), float2 channels, 4x unroll ----
    int half = lane >> 5;
    int l5 = lane & 31;
    int c0 = l5 * 2;
    int hB = l5 >> 2;
    float mB = __shfl(m, hB);
    float sB = __shfl(s, hB);
    float inv = 1.f / fmaxf(sB, 1e-16f);
    float advB = __shfl(advA, hB);
    float eSelfB = __shfl(eSelf, hB);

    float2 acc = make_float2(0.f, 0.f);
    if (half == 0) {
        float p = __expf(eSelfB - mB);
        float2 hv = *(const float2*)(h1 + (size_t)node * 64 + c0);
        acc.x = p * hv.x; acc.y = p * hv.y;
    }
    {
        int i = beg + half;
        for (; i + 6 < end; i += 8) {
            int s0 = csr[i], s1 = csr[i + 2], s2 = csr[i + 4], s3 = csr[i + 6];
            float a0 = asrc1[s0 * 8 + hB], a1 = asrc1[s1 * 8 + hB];
            float a2 = asrc1[s2 * 8 + hB], a3 = asrc1[s3 * 8 + hB];
            float2 g0 = *(const float2*)(h1 + (size_t)s0 * 64 + c0);
            float2 g1 = *(const float2*)(h1 + (size_t)s1 * 64 + c0);
            float2 g2 = *(const float2*)(h1 + (size_t)s2 * 64 + c0);
            float2 g3 = *(const float2*)(h1 + (size_t)s3 * 64 + c0);
            float e0 = a0 + advB; e0 = e0 > 0.f ? e0 : NEG_SLOPE * e0;
            float e1 = a1 + advB; e1 = e1 > 0.f ? e1 : NEG_SLOPE * e1;
            float e2 = a2 + advB; e2 = e2 > 0.f ? e2 : NEG_SLOPE * e2;
            float e3 = a3 + advB; e3 = e3 > 0.f ? e3 : NEG_SLOPE * e3;
            float p0 = __expf(e0 - mB), p1 = __expf(e1 - mB);
            float p2 = __expf(e2 - mB), p3 = __expf(e3 - mB);
            acc.x = fmaf(p0, g0.x, acc.x); acc.y = fmaf(p0, g0.y, acc.y);
            acc.x = fmaf(p1, g1.x, acc.x); acc.y = fmaf(p1, g1.y, acc.y);
            acc.x = fmaf(p2, g2.x, acc.x); acc.y = fmaf(p2, g2.y, acc.y);
            acc.x = fmaf(p3, g3.x, acc.x); acc.y = fmaf(p3, g3.y, acc.y);
        }
        for (; i < end; i += 2) {
            int sn = csr[i];
            float a = asrc1[sn * 8 + hB];
            float2 g = *(const float2*)(h1 + (size_t)sn * 64 + c0);
            float e = a + advB; e = e > 0.f ? e : NEG_SLOPE * e;
            float p = __expf(e - mB);
            acc.x = fmaf(p, g.x, acc.x); acc.y = fmaf(p, g.y, acc.y);
        }
    }
    acc.x += __shfl_xor(acc.x, 32);
    acc.y += __shfl_xor(acc.y, 32);

    float vx = acc.x * inv + s_b1[c0];
    float vy = acc.y * inv + s_b1[c0 + 1];
    vx = vx > 0.f ? vx : __expf(vx) - 1.f;
    vy = vy > 0.f ? vy : __expf(vy) - 1.f;

    float hj[OUT_DIM];
    #pragma unroll
    for (int j = 0; j < OUT_DIM; ++j) {
        float p = vx * w2s[c0][j] + vy * w2s[c0 + 1][j];
        #pragma unroll
        for (int d = 1; d < 32; d <<= 1) p += __shfl_xor(p, d);
        hj[j] = p;
    }
    float a_s = 0.f, a_d = 0.f;
    #pragma unroll
    for (int j = 0; j < OUT_DIM; ++j) { a_s += hj[j] * s_as2[j]; a_d += hj[j] * s_ad2[j]; }
    if (lane < 8) h2[node * 8 + lane] = (lane < OUT_DIM) ? hj[lane] : 0.f;
    if (lane == 0) { asrc2[node] = a_s; adst2[node] = a_d; }
}

// ---------------- Layer-2 edge kernel -> final logits ----------------
__global__ __launch_bounds__(256) void l2_edge_kernel(
    const int* __restrict__ offsets, const int* __restrict__ counts,
    const int* __restrict__ csr,
    const float* __restrict__ asrc2, const float* __restrict__ adst2,
    const float* __restrict__ h2, const float* __restrict__ b2,
    float* __restrict__ out, int n)
{
    int t = threadIdx.x, lane = t & 63;
    int node = blockIdx.x * 4 + (t >> 6);
    if (node >= n) return;
    int beg = offsets[node];
    int end = beg + counts[node];
    float adv = adst2[node];

    float m, s;
    if (lane == 0) {
        float e = asrc2[node] + adv;
        e = e > 0.f ? e : NEG_SLOPE * e;
        m = e; s = 1.f;
    } else { m = -1e30f; s = 0.f; }
    for (int i = beg + lane; i < end; i += 64) {
        int sn = csr[i];
        float e = asrc2[sn] + adv;
        e = e > 0.f ? e : NEG_SLOPE * e;
        if (e > m) { s = s * __expf(m - e) + 1.f; m = e; }
        else        s += __expf(e - m);
    }
    #pragma unroll
    for (int d = 1; d < 64; d <<= 1) {
        float mo = __shfl_xor(m, d), so = __shfl_xor(s, d);
        float mn = fmaxf(m, mo);
        s = s * __expf(m - mn) + so * __expf(mo - mn);
        m = mn;
    }
    float inv = 1.f / fmaxf(s, 1e-16f);

    int c = lane & 7, slot = lane >> 3;
    float acc = 0.f;
    if (slot == 0) {
        float e = asrc2[node] + adv;
        e = e > 0.f ? e : NEG_SLOPE * e;
        acc = __expf(e - m) * h2[node * 8 + c];
    }
    for (int i = beg + slot; i < end; i += 8) {
        int sn = csr[i];
        float e = asrc2[sn] + adv;
        e = e > 0.f ? e : NEG_SLOPE * e;
        acc = fmaf(__expf(e - m), h2[sn * 8 + c], acc);
    }
    #pragma unroll
    for (int d = 8; d < 64; d <<= 1) acc += __shfl_xor(acc, d);
    if (lane < OUT_DIM) out[(size_t)node * OUT_DIM + lane] = acc * inv + b2[lane];
}

// ---------------- launch ----------------
static inline size_t rup256(size_t x) { return (x + 255) & ~(size_t)255; }

extern "C" void kernel_launch(void* const* d_in, const int* in_sizes, int n_in,
                              void* d_out, int out_size, void* d_ws, size_t ws_size,
                              hipStream_t stream)
{
    int n = in_sizes[0] / IN_DIM;     // 50000
    int E = in_sizes[1] / 2;          // 1600000
    int nbuck = (n + 255) >> 8;       // 196

    const float* x   = (const float*)d_in[0];
    const int*   ei  = (const int*)d_in[1];
    const int*   srcv = ei;
    const int*   dstv = ei + E;
    const float* W1  = (const float*)d_in[2];
    const float* as1 = (const float*)d_in[3];
    const float* ad1 = (const float*)d_in[4];
    const float* b1  = (const float*)d_in[5];
    const float* W2  = (const float*)d_in[6];
    const float* as2 = (const float*)d_in[7];
    const float* ad2 = (const float*)d_in[8];
    const float* b2  = (const float*)d_in[9];
    float* out = (float*)d_out;

    char* p = (char*)d_ws;
    auto alloc = [&](size_t bytes) { char* q = p; p += rup256(bytes); return (void*)q; };
    float* h1      = (float*)alloc((size_t)n * 64 * 4);
    float* asrc1   = (float*)alloc((size_t)n * 8 * 4);
    float* adst1   = (float*)alloc((size_t)n * 8 * 4);
    float* h2      = (float*)alloc((size_t)n * 8 * 4);
    float* asrc2   = (float*)alloc((size_t)n * 4);
    float* adst2   = (float*)alloc((size_t)n * 4);
    int*   counts  = (int*)alloc((size_t)n * 4);
    int*   offsets = (int*)alloc(((size_t)n + 1) * 4);
    int*   csr     = (int*)alloc((size_t)E * 4);
    unsigned int* tmp = (unsigned int*)alloc((size_t)E * 4);
    int*   bucketCounts = (int*)alloc(256 * 4);
    int*   bucketBase   = (int*)alloc(257 * 4);
    int*   bucketCursor = (int*)alloc(256 * 4);

    hipMemsetAsync(bucketCounts, 0, 256 * 4, stream);
    bucket_hist_kernel<<<512, 256, 0, stream>>>(dstv, bucketCounts, E, nbuck);
    gemm1_kernel<<<(n + BM - 1) / BM, 256, 0, stream>>>(
        x, W1, as1, ad1, h1, asrc1, adst1, n);
    bucket_scan_kernel<<<1, 256, 0, stream>>>(bucketCounts, bucketBase, bucketCursor, nbuck);
    coarse_scatter_kernel<<<(E + 256 * K3_EPT - 1) / (256 * K3_EPT), 256, 0, stream>>>(
        srcv, dstv, bucketCursor, tmp, E);
    fine_scatter_kernel<<<nbuck, 256, 0, stream>>>(
        tmp, bucketBase, csr, offsets, counts, n);
    l1_edge_kernel<<<(n + 3) / 4, 256, 0, stream>>>(
        offsets, counts, csr, asrc1, adst1, h1, b1, W2, as2, ad2, h2, asrc2, adst2, n);
    l2_edge_kernel<<<(n + 3) / 4, 256, 0, stream>>>(
        offsets, counts, csr, asrc2, adst2, h2, b2, out, n);
}

// Round 7
// 233.188 us; speedup vs baseline: 2.5064x; 1.0204x over previous
//
#include <hip/hip_runtime.h>
#include <hip/hip_bf16.h>

#define IN_DIM 512
#define HEADS 8
#define HID 8
#define OUT_DIM 7
#define NEG_SLOPE 0.2f

// ---------------- GEMM1: h1 = x @ W1  (+ fused asrc1/adst1) ----------------
#define BM 64
#define BK 32
__global__ __launch_bounds__(256) void gemm1_kernel(
    const float* __restrict__ x, const float* __restrict__ W1,
    const float* __restrict__ as1, const float* __restrict__ ad1,
    float* __restrict__ h1, float* __restrict__ asrc1, float* __restrict__ adst1,
    int n)
{
    __shared__ float Xt[BK][BM + 4];
    __shared__ float Ws[BK][64];
    int t = threadIdx.x;
    int col4 = (t & 15) * 4;
    int row4 = (t >> 4) * 4;
    int r0 = blockIdx.x * BM;
    float acc[4][4] = {{0.f,0.f,0.f,0.f},{0.f,0.f,0.f,0.f},{0.f,0.f,0.f,0.f},{0.f,0.f,0.f,0.f}};

    for (int k0 = 0; k0 < IN_DIM; k0 += BK) {
        __syncthreads();
        {
            const float4* w4 = (const float4*)(W1 + k0 * 64);
            float4* ws4 = (float4*)(&Ws[0][0]);
            ws4[t] = w4[t];
            ws4[t + 256] = w4[t + 256];
        }
        #pragma unroll
        for (int j = 0; j < 2; ++j) {
            int idx = t + j * 256;
            int row = idx >> 3, kq = idx & 7;
            int gr = r0 + row;
            float4 v = make_float4(0.f, 0.f, 0.f, 0.f);
            if (gr < n) v = *(const float4*)(x + (size_t)gr * IN_DIM + k0 + kq * 4);
            Xt[kq * 4 + 0][row] = v.x;
            Xt[kq * 4 + 1][row] = v.y;
            Xt[kq * 4 + 2][row] = v.z;
            Xt[kq * 4 + 3][row] = v.w;
        }
        __syncthreads();
        #pragma unroll
        for (int kk = 0; kk < BK; ++kk) {
            float4 xv = *(const float4*)(&Xt[kk][row4]);
            float4 wv = *(const float4*)(&Ws[kk][col4]);
            acc[0][0] = fmaf(xv.x, wv.x, acc[0][0]);
            acc[0][1] = fmaf(xv.x, wv.y, acc[0][1]);
            acc[0][2] = fmaf(xv.x, wv.z, acc[0][2]);
            acc[0][3] = fmaf(xv.x, wv.w, acc[0][3]);
            acc[1][0] = fmaf(xv.y, wv.x, acc[1][0]);
            acc[1][1] = fmaf(xv.y, wv.y, acc[1][1]);
            acc[1][2] = fmaf(xv.y, wv.z, acc[1][2]);
            acc[1][3] = fmaf(xv.y, wv.w, acc[1][3]);
            acc[2][0] = fmaf(xv.z, wv.x, acc[2][0]);
            acc[2][1] = fmaf(xv.z, wv.y, acc[2][1]);
            acc[2][2] = fmaf(xv.z, wv.z, acc[2][2]);
            acc[2][3] = fmaf(xv.z, wv.w, acc[2][3]);
            acc[3][0] = fmaf(xv.w, wv.x, acc[3][0]);
            acc[3][1] = fmaf(xv.w, wv.y, acc[3][1]);
            acc[3][2] = fmaf(xv.w, wv.z, acc[3][2]);
            acc[3][3] = fmaf(xv.w, wv.w, acc[3][3]);
        }
    }
    int head = col4 >> 3;
    float4 asv = *(const float4*)(as1 + col4);
    float4 adv = *(const float4*)(ad1 + col4);
    #pragma unroll
    for (int r = 0; r < 4; ++r) {
        int gr = r0 + row4 + r;
        if (gr < n) {
            *(float4*)(h1 + (size_t)gr * 64 + col4) =
                make_float4(acc[r][0], acc[r][1], acc[r][2], acc[r][3]);
            float pa = acc[r][0] * asv.x + acc[r][1] * asv.y + acc[r][2] * asv.z + acc[r][3] * asv.w;
            float pd = acc[r][0] * adv.x + acc[r][1] * adv.y + acc[r][2] * adv.z + acc[r][3] * adv.w;
            pa += __shfl_xor(pa, 1);
            pd += __shfl_xor(pd, 1);
            if ((t & 1) == 0) {
                asrc1[gr * 8 + head] = pa;
                adst1[gr * 8 + head] = pd;
            }
        }
    }
}

// ---------------- CSR build: bucketed two-stage ----------------
__global__ __launch_bounds__(256) void bucket_hist_kernel(
    const int* __restrict__ dst, int* __restrict__ bucketCounts, int E, int nbuck)
{
    __shared__ int cnt[256];
    int t = threadIdx.x;
    cnt[t] = 0;
    __syncthreads();
    int i = blockIdx.x * blockDim.x + t;
    int stride = gridDim.x * blockDim.x;
    for (; i < E; i += stride) atomicAdd(&cnt[dst[i] >> 8], 1);
    __syncthreads();
    if (t < nbuck && cnt[t]) atomicAdd(&bucketCounts[t], cnt[t]);
}

__global__ __launch_bounds__(256) void bucket_scan_kernel(
    const int* __restrict__ bucketCounts, int* __restrict__ bucketBase,
    int* __restrict__ bucketCursor, int nbuck)
{
    __shared__ int wsum[4];
    int t = threadIdx.x, lane = t & 63, w = t >> 6;
    int c = (t < nbuck) ? bucketCounts[t] : 0;
    int inc = c;
    #pragma unroll
    for (int d = 1; d < 64; d <<= 1) {
        int u = __shfl_up(inc, d);
        if (lane >= d) inc += u;
    }
    if (lane == 63) wsum[w] = inc;
    __syncthreads();
    if (t == 0) { int run = 0; for (int k = 0; k < 4; ++k) { int tmp = wsum[k]; wsum[k] = run; run += tmp; } }
    __syncthreads();
    int excl = inc - c + wsum[w];
    if (t < nbuck) { bucketBase[t] = excl; bucketCursor[t] = excl; }
    if (t == nbuck) bucketBase[t] = excl;
}

#define K3_EPT 16
__global__ __launch_bounds__(256) void coarse_scatter_kernel(
    const int* __restrict__ src, const int* __restrict__ dst,
    int* __restrict__ bucketCursor, unsigned int* __restrict__ tmp, int E)
{
    __shared__ int cnt[256];
    __shared__ int gbase[256];
    int t = threadIdx.x;
    cnt[t] = 0;
    __syncthreads();
    int base = blockIdx.x * (256 * K3_EPT);
    unsigned int pk[K3_EPT];
    unsigned int meta[K3_EPT];
    #pragma unroll
    for (int j = 0; j < K3_EPT; ++j) {
        int i = base + t + j * 256;
        if (i < E) {
            int d = dst[i], s = src[i];
            int b = d >> 8;
            pk[j] = ((unsigned)s << 16) | (unsigned)(d & 0xFF);
            int r = atomicAdd(&cnt[b], 1);
            meta[j] = ((unsigned)r << 8) | (unsigned)b;
        } else {
            meta[j] = 0xFFFFFFFFu; pk[j] = 0;
        }
    }
    __syncthreads();
    if (cnt[t] > 0) gbase[t] = atomicAdd(&bucketCursor[t], cnt[t]);
    __syncthreads();
    #pragma unroll
    for (int j = 0; j < K3_EPT; ++j) {
        if (meta[j] != 0xFFFFFFFFu) {
            int b = meta[j] & 0xFF;
            int r = meta[j] >> 8;
            tmp[gbase[b] + r] = pk[j];
        }
    }
}

__global__ __launch_bounds__(256) void fine_scatter_kernel(
    const unsigned int* __restrict__ tmp, const int* __restrict__ bucketBase,
    int* __restrict__ csr, int* __restrict__ offsets, int* __restrict__ counts, int n)
{
    __shared__ int cnt[256];
    __shared__ int cur[256];
    __shared__ int wsum[4];
    int b = blockIdx.x;
    int t = threadIdx.x, lane = t & 63, w = t >> 6;
    int beg = bucketBase[b], end = bucketBase[b + 1];
    cnt[t] = 0;
    __syncthreads();
    for (int i = beg + t; i < end; i += 256)
        atomicAdd(&cnt[tmp[i] & 0xFF], 1);
    __syncthreads();
    int c = cnt[t];
    int inc = c;
    #pragma unroll
    for (int d = 1; d < 64; d <<= 1) {
        int u = __shfl_up(inc, d);
        if (lane >= d) inc += u;
    }
    if (lane == 63) wsum[w] = inc;
    __syncthreads();
    if (t == 0) { int run = 0; for (int k = 0; k < 4; ++k) { int tt = wsum[k]; wsum[k] = run; run += tt; } }
    __syncthreads();
    int excl = inc - c + wsum[w];
    int node = b * 256 + t;
    if (node < n) { offsets[node] = beg + excl; counts[node] = c; }
    cur[t] = excl;
    __syncthreads();
    for (int i = beg + t; i < end; i += 256) {
        unsigned int p = tmp[i];
        int r = atomicAdd(&cur[p & 0xFF], 1);
        csr[beg + r] = (int)(p >> 16);
    }
}

// ---------------- Layer-1 edge kernel ----------------
// Phase A: pure per-head MAX over edges (no exp) + cache post-leaky e in LDS.
// Phase B: p = exp(e_lds - m); acc += p*h1; ssum += p  (denominator fused).
#define MAXDEG 64
__global__ __launch_bounds__(256) void l1_edge_kernel(
    const int* __restrict__ offsets, const int* __restrict__ counts,
    const int* __restrict__ csr,
    const float* __restrict__ asrc1, const float* __restrict__ adst1,
    const float* __restrict__ h1, const float* __restrict__ b1,
    const float* __restrict__ W2, const float* __restrict__ as2,
    const float* __restrict__ ad2,
    float* __restrict__ h2, float* __restrict__ asrc2, float* __restrict__ adst2,
    int n)
{
    __shared__ float e_lds[4][MAXDEG * 8];   // 8 KB: [node_local][edge*8+head]
    __shared__ float w2s[64][9];
    __shared__ float s_as2[8], s_ad2[8], s_b1[64];
    int t = threadIdx.x;
    if (t < 64) {
        #pragma unroll
        for (int j = 0; j < OUT_DIM; ++j) w2s[t][j] = W2[t * OUT_DIM + j];
        s_b1[t] = b1[t];
        if (t < OUT_DIM) { s_as2[t] = as2[t]; s_ad2[t] = ad2[t]; }
    }
    __syncthreads();

    int lane = t & 63;
    int nl = t >> 6;
    int node = blockIdx.x * 4 + nl;
    if (node >= n) return;
    int beg = offsets[node];
    int deg = counts[node];
    int jmax = deg < MAXDEG ? deg : MAXDEG;
    float* el = &e_lds[nl][0];

    // ---- Phase A: per-head max. lane = slot*8 + h ----
    int hA = lane & 7, slot = lane >> 3;
    float advA = adst1[node * 8 + hA];
    float m = -1e30f, eSelf = 0.f;
    if (slot == 0) {
        float e = asrc1[node * 8 + hA] + advA;
        e = e > 0.f ? e : NEG_SLOPE * e;
        eSelf = e; m = e;
    }
    {
        int j = slot;
        for (; j + 8 < jmax; j += 16) {   // 2x unroll
            int sa = csr[beg + j], sb = csr[beg + j + 8];
            float ea = asrc1[sa * 8 + hA] + advA;
            float eb = asrc1[sb * 8 + hA] + advA;
            ea = ea > 0.f ? ea : NEG_SLOPE * ea;
            eb = eb > 0.f ? eb : NEG_SLOPE * eb;
            el[j * 8 + hA] = ea;
            el[(j + 8) * 8 + hA] = eb;
            m = fmaxf(m, fmaxf(ea, eb));
        }
        for (; j < jmax; j += 8) {
            int sn = csr[beg + j];
            float e = asrc1[sn * 8 + hA] + advA;
            e = e > 0.f ? e : NEG_SLOPE * e;
            el[j * 8 + hA] = e;
            m = fmaxf(m, e);
        }
        for (; j < deg; j += 8) {        // overflow (deg > MAXDEG): no cache
            int sn = csr[beg + j];
            float e = asrc1[sn * 8 + hA] + advA;
            e = e > 0.f ? e : NEG_SLOPE * e;
            m = fmaxf(m, e);
        }
    }
    #pragma unroll
    for (int d = 8; d < 64; d <<= 1) m = fmaxf(m, __shfl_xor(m, d));
    // lane k holds max for head k&7; lanes 0..7 hold eSelf/advA for heads 0..7

    // ---- Phase B: halves process alternating edges; float2 channels ----
    int half = lane >> 5;
    int l5 = lane & 31;
    int c0 = l5 * 2;
    int hB = l5 >> 2;
    float mB = __shfl(m, hB);
    float eSelfB = __shfl(eSelf, hB);
    float advB = __shfl(advA, hB);

    float2 acc = make_float2(0.f, 0.f);
    float ssum = 0.f;
    if (half == 0) {
        float p = __expf(eSelfB - mB);
        float2 hv = *(const float2*)(h1 + (size_t)node * 64 + c0);
        acc.x = p * hv.x; acc.y = p * hv.y;
        ssum = p;
    }
    {
        int j = half;
        for (; j + 6 < jmax; j += 8) {   // 4 edges per half per round
            int s0 = csr[beg + j], s1 = csr[beg + j + 2];
            int s2 = csr[beg + j + 4], s3 = csr[beg + j + 6];
            float e0 = el[j * 8 + hB],       e1 = el[(j + 2) * 8 + hB];
            float e2 = el[(j + 4) * 8 + hB], e3 = el[(j + 6) * 8 + hB];
            float2 g0 = *(const float2*)(h1 + (size_t)s0 * 64 + c0);
            float2 g1 = *(const float2*)(h1 + (size_t)s1 * 64 + c0);
            float2 g2 = *(const float2*)(h1 + (size_t)s2 * 64 + c0);
            float2 g3 = *(const float2*)(h1 + (size_t)s3 * 64 + c0);
            float p0 = __expf(e0 - mB), p1 = __expf(e1 - mB);
            float p2 = __expf(e2 - mB), p3 = __expf(e3 - mB);
            acc.x = fmaf(p0, g0.x, acc.x); acc.y = fmaf(p0, g0.y, acc.y);
            acc.x = fmaf(p1, g1.x, acc.x); acc.y = fmaf(p1, g1.y, acc.y);
            acc.x = fmaf(p2, g2.x, acc.x); acc.y = fmaf(p2, g2.y, acc.y);
            acc.x = fmaf(p3, g3.x, acc.x); acc.y = fmaf(p3, g3.y, acc.y);
            ssum += p0 + p1 + p2 + p3;
        }
        for (; j < jmax; j += 2) {       // cached tail
            int sn = csr[beg + j];
            float e = el[j * 8 + hB];
            float2 g = *(const float2*)(h1 + (size_t)sn * 64 + c0);
            float p = __expf(e - mB);
            acc.x = fmaf(p, g.x, acc.x); acc.y = fmaf(p, g.y, acc.y);
            ssum += p;
        }
        for (; j < deg; j += 2) {        // overflow: recompute e
            int sn = csr[beg + j];
            float a = asrc1[sn * 8 + hB];
            float2 g = *(const float2*)(h1 + (size_t)sn * 64 + c0);
            float e = a + advB; e = e > 0.f ? e : NEG_SLOPE * e;
            float p = __expf(e - mB);
            acc.x = fmaf(p, g.x, acc.x); acc.y = fmaf(p, g.y, acc.y);
            ssum += p;
        }
    }
    acc.x += __shfl_xor(acc.x, 32);
    acc.y += __shfl_xor(acc.y, 32);
    ssum  += __shfl_xor(ssum, 32);
    float inv = 1.f / fmaxf(ssum, 1e-16f);

    float vx = acc.x * inv + s_b1[c0];
    float vy = acc.y * inv + s_b1[c0 + 1];
    vx = vx > 0.f ? vx : __expf(vx) - 1.f;
    vy = vy > 0.f ? vy : __expf(vy) - 1.f;

    float hj[OUT_DIM];
    #pragma unroll
    for (int j = 0; j < OUT_DIM; ++j) {
        float p = vx * w2s[c0][j] + vy * w2s[c0 + 1][j];
        #pragma unroll
        for (int d = 1; d < 32; d <<= 1) p += __shfl_xor(p, d);
        hj[j] = p;
    }
    float a_s = 0.f, a_d = 0.f;
    #pragma unroll
    for (int j = 0; j < OUT_DIM; ++j) { a_s += hj[j] * s_as2[j]; a_d += hj[j] * s_ad2[j]; }
    if (lane < 8) h2[node * 8 + lane] = (lane < OUT_DIM) ? hj[lane] : 0.f;
    if (lane == 0) { asrc2[node] = a_s; adst2[node] = a_d; }
}

// ---------------- Layer-2 edge kernel -> final logits ----------------
__global__ __launch_bounds__(256) void l2_edge_kernel(
    const int* __restrict__ offsets, const int* __restrict__ counts,
    const int* __restrict__ csr,
    const float* __restrict__ asrc2, const float* __restrict__ adst2,
    const float* __restrict__ h2, const float* __restrict__ b2,
    float* __restrict__ out, int n)
{
    int t = threadIdx.x, lane = t & 63;
    int node = blockIdx.x * 4 + (t >> 6);
    if (node >= n) return;
    int beg = offsets[node];
    int end = beg + counts[node];
    float adv = adst2[node];

    float m, s;
    if (lane == 0) {
        float e = asrc2[node] + adv;
        e = e > 0.f ? e : NEG_SLOPE * e;
        m = e; s = 1.f;
    } else { m = -1e30f; s = 0.f; }
    for (int i = beg + lane; i < end; i += 64) {
        int sn = csr[i];
        float e = asrc2[sn] + adv;
        e = e > 0.f ? e : NEG_SLOPE * e;
        if (e > m) { s = s * __expf(m - e) + 1.f; m = e; }
        else        s += __expf(e - m);
    }
    #pragma unroll
    for (int d = 1; d < 64; d <<= 1) {
        float mo = __shfl_xor(m, d), so = __shfl_xor(s, d);
        float mn = fmaxf(m, mo);
        s = s * __expf(m - mn) + so * __expf(mo - mn);
        m = mn;
    }
    float inv = 1.f / fmaxf(s, 1e-16f);

    int c = lane & 7, slot = lane >> 3;
    float acc = 0.f;
    if (slot == 0) {
        float e = asrc2[node] + adv;
        e = e > 0.f ? e : NEG_SLOPE * e;
        acc = __expf(e - m) * h2[node * 8 + c];
    }
    for (int i = beg + slot; i < end; i += 8) {
        int sn = csr[i];
        float e = asrc2[sn] + adv;
        e = e > 0.f ? e : NEG_SLOPE * e;
        acc = fmaf(__expf(e - m), h2[sn * 8 + c], acc);
    }
    #pragma unroll
    for (int d = 8; d < 64; d <<= 1) acc += __shfl_xor(acc, d);
    if (lane < OUT_DIM) out[(size_t)node * OUT_DIM + lane] = acc * inv + b2[lane];
}

// ---------------- launch ----------------
static inline size_t rup256(size_t x) { return (x + 255) & ~(size_t)255; }

extern "C" void kernel_launch(void* const* d_in, const int* in_sizes, int n_in,
                              void* d_out, int out_size, void* d_ws, size_t ws_size,
                              hipStream_t stream)
{
    int n = in_sizes[0] / IN_DIM;     // 50000
    int E = in_sizes[1] / 2;          // 1600000
    int nbuck = (n + 255) >> 8;       // 196

    const float* x   = (const float*)d_in[0];
    const int*   ei  = (const int*)d_in[1];
    const int*   srcv = ei;
    const int*   dstv = ei + E;
    const float* W1  = (const float*)d_in[2];
    const float* as1 = (const float*)d_in[3];
    const float* ad1 = (const float*)d_in[4];
    const float* b1  = (const float*)d_in[5];
    const float* W2  = (const float*)d_in[6];
    const float* as2 = (const float*)d_in[7];
    const float* ad2 = (const float*)d_in[8];
    const float* b2  = (const float*)d_in[9];
    float* out = (float*)d_out;

    char* p = (char*)d_ws;
    auto alloc = [&](size_t bytes) { char* q = p; p += rup256(bytes); return (void*)q; };
    float* h1      = (float*)alloc((size_t)n * 64 * 4);
    float* asrc1   = (float*)alloc((size_t)n * 8 * 4);
    float* adst1   = (float*)alloc((size_t)n * 8 * 4);
    float* h2      = (float*)alloc((size_t)n * 8 * 4);
    float* asrc2   = (float*)alloc((size_t)n * 4);
    float* adst2   = (float*)alloc((size_t)n * 4);
    int*   counts  = (int*)alloc((size_t)n * 4);
    int*   offsets = (int*)alloc(((size_t)n + 1) * 4);
    int*   csr     = (int*)alloc((size_t)E * 4);
    unsigned int* tmp = (unsigned int*)alloc((size_t)E * 4);
    int*   bucketCounts = (int*)alloc(256 * 4);
    int*   bucketBase   = (int*)alloc(257 * 4);
    int*   bucketCursor = (int*)alloc(256 * 4);

    hipMemsetAsync(bucketCounts, 0, 256 * 4, stream);
    bucket_hist_kernel<<<512, 256, 0, stream>>>(dstv, bucketCounts, E, nbuck);
    gemm1_kernel<<<(n + BM - 1) / BM, 256, 0, stream>>>(
        x, W1, as1, ad1, h1, asrc1, adst1, n);
    bucket_scan_kernel<<<1, 256, 0, stream>>>(bucketCounts, bucketBase, bucketCursor, nbuck);
    coarse_scatter_kernel<<<(E + 256 * K3_EPT - 1) / (256 * K3_EPT), 256, 0, stream>>>(
        srcv, dstv, bucketCursor, tmp, E);
    fine_scatter_kernel<<<nbuck, 256, 0, stream>>>(
        tmp, bucketBase, csr, offsets, counts, n);
    l1_edge_kernel<<<(n + 3) / 4, 256, 0, stream>>>(
        offsets, counts, csr, asrc1, adst1, h1, b1, W2, as2, ad2, h2, asrc2, adst2, n);
    l2_edge_kernel<<<(n + 3) / 4, 256, 0, stream>>>(
        offsets, counts, csr, asrc2, adst2, h2, b2, out, n);
}